// Round 17
// baseline (1750.742 us; speedup 1.0000x reference)
//
#include <hip/hip_runtime.h>
#include <stdint.h>

// Problem constants (B=32, C1=64, C2=16, C3=16, N=8)
#define EPSF    1e-10f
#define NCHAIN  2048        // B*C1
#define SEQ     256         // C2*C3
#define NMAT    (NCHAIN*SEQ)

// X^{-1} per matrix, produced by helper waves during the fm scan phase,
// consumed by the dist phase (134 MB, fully rewritten each call).
__device__ float g_xinv[(size_t)NMAT * 64];

__device__ __forceinline__ float rcpf(float x) { return __builtin_amdgcn_rcpf(x); }
__device__ __forceinline__ float rsqf(float x) { return __builtin_amdgcn_rsqf(x); }
__device__ __forceinline__ float exp2f_(float x) { return __builtin_amdgcn_exp2f(x); }
__device__ __forceinline__ float log2f_(float x) { return __builtin_amdgcn_logf(x); }

// bpermute with pre-shifted (byte) address
__device__ __forceinline__ float bpf(int addr4, float v) {
    return __int_as_float(__builtin_amdgcn_ds_bpermute(addr4, __float_as_int(v)));
}
// uniform-lane broadcast (diagonal pivots)
__device__ __forceinline__ float rlf(float v, int srcLane) {
    return __int_as_float(__builtin_amdgcn_readlane(__float_as_int(v), srcLane));
}
// lane-XOR shuffle via ds_swizzle immediate (DS pipe), mask < 32
template<int MASK>
__device__ __forceinline__ float sxf(float v) {
    static_assert(MASK > 0 && MASK < 32, "swizzle mask");
    return __int_as_float(__builtin_amdgcn_ds_swizzle(
        __float_as_int(v), (MASK << 10) | 0x1F));
}
// DPP mov: cross-lane on the VALU pipe, zero DS cost.
template<int CTRL, int RMASK = 0xF, bool BC = true>
__device__ __forceinline__ float dppf(float v) {
    return __int_as_float(__builtin_amdgcn_update_dpp(
        0, __float_as_int(v), CTRL, RMASK, 0xF, BC));
}
// lane XOR M (M=1..7, column bits) entirely via DPP
template<int M>
__device__ __forceinline__ float cxf(float v) {
    if constexpr      (M == 1) return dppf<0xB1>(v);
    else if constexpr (M == 2) return dppf<0x4E>(v);
    else if constexpr (M == 3) return dppf<0x1B>(v);
    else if constexpr (M == 4) return dppf<0x141>(dppf<0x1B>(v));  // 7^3
    else if constexpr (M == 5) return dppf<0x141>(dppf<0x4E>(v));  // 7^2
    else if constexpr (M == 6) return dppf<0x141>(dppf<0xB1>(v));  // 7^1
    else                       return dppf<0x141>(v);              // 7
}
// dist variant: for the 2-DPP masks use one ds_swizzle instead (dist is
// VALU-bound; bit-exact same permutation)
template<int M>
__device__ __forceinline__ float cxd(float v) {
    if constexpr (M == 4 || M == 5 || M == 6) return sxf<M>(v);
    else                                      return cxf<M>(v);
}
// lane XOR (M<<3) (row bits): M=1 is DPP, M=2,3 swizzle, M>=4 bpermute
template<int M>
__device__ __forceinline__ float rxf(float v, int lane4) {
    if constexpr      (M == 1)       return dppf<0x128>(v);
    else if constexpr ((M << 3) < 32) return sxf<(M << 3)>(v);
    else                              return bpf(lane4 ^ (M << 5), v);
}
// lane XOR (M*9) (row+col bits): M=1 via 2 DPP, M=2,3 swizzle, M>=4 bpermute
template<int M>
__device__ __forceinline__ float dxf(float v, int lane4) {
    if constexpr      (M == 1)       return dppf<0xB1>(dppf<0x128>(v));
    else if constexpr ((M * 9) < 32)  return sxf<(M * 9)>(v);
    else                              return bpf(lane4 ^ (M * 36), v);
}

// wave64 sum -> lane 63 holds the total
__device__ __forceinline__ float wave_sum63(float v) {
    v += dppf<0x111>(v);                    // += lane-1   (row_shr:1)
    v += dppf<0x112>(v);                    // += lane-2
    v += dppf<0x114>(v);                    // += lane-4
    v += dppf<0x118>(v);                    // += lane-8   -> lane15/31/47/63
    v += dppf<0x142, 0xA, false>(v);        // bcast15 into rows 1,3
    v += dppf<0x143, 0xC, false>(v);        // bcast31 into rows 2,3
    return v;
}

// 8-float dot from two LDS rows (4x ds_read_b128, 2-way bank alias = free)
__device__ __forceinline__ float dot8(const float* __restrict__ a,
                                      const float* __restrict__ b) {
    const float4 a0 = *reinterpret_cast<const float4*>(a);
    const float4 a1 = *reinterpret_cast<const float4*>(a + 4);
    const float4 b0 = *reinterpret_cast<const float4*>(b);
    const float4 b1 = *reinterpret_cast<const float4*>(b + 4);
    float s = a0.x * b0.x;
    s = fmaf(a0.y, b0.y, s); s = fmaf(a0.z, b0.z, s); s = fmaf(a0.w, b0.w, s);
    s = fmaf(a1.x, b1.x, s); s = fmaf(a1.y, b1.y, s); s = fmaf(a1.z, b1.z, s);
    s = fmaf(a1.w, b1.w, s);
    return s;
}

// Jacobi rotation params for pair {j, j^m}. dj = own diag, dm = partner
// diag, apq = pair off-diagonal, sg = tie-break sign (+1 for pair-second).
__device__ __forceinline__ void jrot2(float dj, float dm, float apq, float sg,
                                      float &c, float &bs) {
    const float dd = dj - dm;
    const float h  = apq + apq;
    const float r2 = fmaf(dd, dd, fmaf(h, h, 1e-36f));
    const float rr = rsqf(r2);                          // 1/r
    const float c2 = fmaf(0.5f * fabsf(dd), rr, 0.5f);  // cos^2 = (1+|d|/r)/2
    const float ic = rsqf(c2);                          // 1/c
    const float chi = (dd != 0.0f) ? copysignf(1.0f, dd) : sg;
    const bool  tiny = r2 < 1e-33f;
    c  = tiny ? 1.0f : c2 * ic;                         // sqrt(c2)
    bs = tiny ? 0.0f : apq * chi * rr * ic;             // s*sign
}

// ---- fm round, chain-shortened (2 DS trips serial): all A-neighbor reads
// reference the PRE-round A (parallel with the aqj gather); t1 is formed
// in-lane (bitwise identical to lane (i^M,j)'s col update since column
// params are column-replicated).
template<int M>
__device__ __forceinline__ void jround_fm(float &A, float &W, float &D,
                                          const int lane4, const int j36,
                                          const int tr4, const float sg) {
    const float dmj = cxf<M>(D);                // DPP (parallel)
    const float aqj = bpf(j36 ^ (M << 2), A);   // A[j, j^M] gather: chain head
    const float Ax  = cxf<M>(A);                // A[i,   j^M]  (parallel)
    const float Ay  = rxf<M>(A, lane4);         // A[i^M, j  ]  (parallel)
    const float Az  = dxf<M>(A, lane4);         // A[i^M, j^M]  (parallel)
    const float Wc  = cxf<M>(W);                // (parallel)
    float aj, bj;
    jrot2(D, dmj, aqj, sg, aj, bj);
    const float ai = bpf(tr4, aj);              // chain: 2nd (last) DS trip
    const float bi = bpf(tr4, bj);
    const float t0 = fmaf(bj, Ax, aj * A);      // col update, row i
    const float t1 = fmaf(bj, Az, aj * Ay);     // col update, row i^M
    A = fmaf(bi, t1, ai * t0);                  // row update
    W = fmaf(bj, Wc, aj * W);
    const float d0 = fmaf(bj, aqj, aj * D);
    const float d1 = fmaf(bj, dmj, aj * aqj);
    D = fmaf(bj, d1, aj * d0);
}

// ---- dist round (R7-proven thr form): fewest VALU ops; dist phase is
// VALU-issue-bound at full occupancy so cross-lane work rides the DS pipe.
template<int M>
__device__ __forceinline__ void jround_d(float &A, float &W, float &D,
                                         const int lane4, const int j36,
                                         const int tr4, const float sg) {
    const float dmj = cxd<M>(D);
    const float aqj = bpf(j36 ^ (M << 2), A);   // DS gather
    float aj, bj;
    jrot2(D, dmj, aqj, sg, aj, bj);
    const float ai = bpf(tr4, aj);              // row params = transpose: DS
    const float bi = bpf(tr4, bj);              // DS
    const float Ac = cxd<M>(A);
    A = fmaf(bj, Ac, aj * A);                   // A <- A J
    const float Ar = rxf<M>(A, lane4);          // post-col-update read
    A = fmaf(bi, Ar, ai * A);                   // A <- J^T A
    const float Wc = cxd<M>(W);
    W = fmaf(bj, Wc, aj * W);
    const float d0 = fmaf(bj, aqj, aj * D);
    const float d1 = fmaf(bj, dmj, aj * aqj);
    D = fmaf(bj, d1, aj * d0);
}

// ---------------- Fused kernel: one block = one chain -------------------
// Phase 1: wave 0 runs the fm scan (inverse-factor recursion, adaptive
//          4/3 sweeps -- R13/R15 accuracy boundaries respected); waves
//          1-3 invert the chain's 256 X matrices into g_xinv (independent
//          of FM, rides the fm phase's idle issue slots).
// Phase 2 (after one block barrier): all 4 waves compute the GL-metric
//          distances, A = X^{-1} F via one LDS matmul (no per-matrix GJ),
//          F handed off through LDS.
__global__ void __launch_bounds__(256, 8)
fused_kernel(const float* __restrict__ x, float* __restrict__ out) {
    __shared__ __align__(16) float sF[64];               // FM (phase 2, RO)
    __shared__ __align__(16) float sXr[4][64];           // per-wave slots
    __shared__ __align__(16) float sAr[4][64];
    __shared__ __align__(16) float sAc[4][64];
    __shared__ __align__(16) float sVc[4][64];
    __shared__ __align__(16) float sTc[4][64];

    const int wave = threadIdx.x >> 6;
    const int lane = threadIdx.x & 63;
    const int i = lane >> 3, j = lane & 7;
    const int lane4 = lane << 2;
    const int i32_ = i << 5, j4 = j << 2, i4 = i << 2;
    const int i36 = i * 36, j36 = j * 36;
    const int i8f = i << 3, j8f = j << 3;
    const int tr4 = ((j << 3) + i) << 2;
    const int chain = blockIdx.x;

    const float sg1 = (lane & 1) ? 1.0f : -1.0f;
    const float sg2 = (lane & 2) ? 1.0f : -1.0f;
    const float sg4 = (lane & 4) ? 1.0f : -1.0f;

    const float* __restrict__ base = x + (size_t)chain * (SEQ * 64);

    if (wave == 0) {
        // ================= Phase 1a: fm scan (wave 0) ===================
        float* __restrict__ bufX = sXr[0];
        float* __restrict__ bufF = sAr[0];
        float* __restrict__ bufW = sAc[0];

        // init: Fi = D^{-1/2} L_u^{-1} from X_1 (one-sided elimination)
        float Mv = base[lane];
        float Ev = (i == j) ? 1.0f : 0.0f;
        #pragma unroll
        for (int kk = 0; kk < 8; ++kk) {
            const float piv = rlf(Mv, kk * 9);
            const float rp  = rcpf(piv);
            const float Mik = bpf(i32_ + (kk << 2), Mv);
            const float Mkj = bpf((kk << 5) + j4,   Mv);
            const float Ekj = bpf((kk << 5) + j4,   Ev);
            const float mi  = (i > kk) ? Mik * rp : 0.0f;
            Mv = fmaf(-mi, Mkj, Mv);
            Ev = fmaf(-mi, Ekj, Ev);
        }
        float Fi = rsqf(bpf(i36, Mv)) * Ev;    // D^{-1/2} L_u^{-1}

        float Xnext = base[(1 << 6) + lane];   // prefetch step input

        #pragma unroll 1
        for (int k = 1; k < SEQ; ++k) {
            const float Xv = Xnext;
            const int kn = (k + 1 < SEQ) ? (k + 1) : k;
            Xnext = base[(kn << 6) + lane];
            const float wk = rcpf((float)(k + 1));

            // B = Fi X Fi^T via LDS matmuls (X symmetric)
            bufX[lane] = Xv;
            bufF[lane] = Fi;
            const float Wv = dot8(bufF + i8f, bufX + j8f);   // (Fi X)_ij
            bufW[lane] = Wv;
            float Bv = dot8(bufW + i8f, bufF + j8f);         // (W Fi^T)_ij
            Bv = 0.5f * (Bv + bpf(tr4, Bv));

            // eigh(B): V (from I), lam in D -- adaptive sweeps (4/3)
            float D = bpf(j36, Bv);
            float V = (i == j) ? 1.0f : 0.0f;
            const int nswp = (k < 12) ? 4 : 3;
            #pragma unroll 1
            for (int sw = 0; sw < nswp; ++sw) {
                jround_fm<1>(Bv, V, D, lane4, j36, tr4, sg1);
                jround_fm<2>(Bv, V, D, lane4, j36, tr4, sg2);
                jround_fm<3>(Bv, V, D, lane4, j36, tr4, sg2);
                jround_fm<4>(Bv, V, D, lane4, j36, tr4, sg4);
                jround_fm<5>(Bv, V, D, lane4, j36, tr4, sg4);
                jround_fm<6>(Bv, V, D, lane4, j36, tr4, sg4);
                jround_fm<7>(Bv, V, D, lane4, j36, tr4, sg4);
            }

            // Fi' = diag(lam^{-wk/2}) V^T Fi
            const float lamI = fmaxf(bpf(i4, D), EPSF);
            const float si   = exp2f_(-0.5f * wk * log2f_(lamI));
            bufW[j8f + i] = V;                 // V col-major
            bufX[j8f + i] = Fi;                // Fi col-major
            Fi = si * dot8(bufW + i8f, bufX + j8f);
        }

        // M = (Fi^T Fi)^{-1} via Gauss-Jordan -> shared F
        bufX[j8f + i] = Fi;
        float Gv = dot8(bufX + i8f, bufX + j8f);
        float Mw = (i == j) ? 1.0f : 0.0f;
        #pragma unroll
        for (int kk = 0; kk < 8; ++kk) {
            const float pr  = rcpf(rlf(Gv, kk * 9));
            const float gk  = bpf((kk << 5) + j4, Gv) * pr;
            const float mk  = bpf((kk << 5) + j4, Mw) * pr;
            const float gik = bpf(i32_ + (kk << 2), Gv);
            const bool  isk = (i == kk);
            Gv = isk ? gk : fmaf(-gik, gk, Gv);
            Mw = isk ? mk : fmaf(-gik, mk, Mw);
        }
        sF[lane] = Mw;
    } else {
        // ============ Phase 1b: X^{-1} precompute (waves 1-3) ===========
        #pragma unroll 1
        for (int t = wave - 1; t < SEQ; t += 3) {
            const size_t gid = (((size_t)chain << 8) + t) * 64;
            float Xw = x[(size_t)chain * (SEQ * 64) + (t << 6) + lane];
            float Yv = (i == j) ? 1.0f : 0.0f;
            #pragma unroll
            for (int k = 0; k < 8; ++k) {
                const float pr  = rcpf(rlf(Xw, k * 9));
                const float xk  = bpf((k << 5) + j4, Xw) * pr;
                const float yk  = bpf((k << 5) + j4, Yv) * pr;
                const float xik = bpf(i32_ + (k << 2), Xw);
                const bool  isk = (i == k);
                Xw = isk ? xk : fmaf(-xik, xk, Xw);
                Yv = isk ? yk : fmaf(-xik, yk, Yv);
            }
            g_xinv[gid + lane] = Yv;
        }
    }

    __syncthreads();

    // ================= Phase 2: distances (all 4 waves) =================
    float* __restrict__ xinvR = sXr[wave];
    float* __restrict__ aRow  = sAr[wave];
    float* __restrict__ aCol  = sAc[wave];
    float* __restrict__ vCol  = sVc[wave];
    float* __restrict__ tCol  = sTc[wave];

    float Xi = g_xinv[(((size_t)chain << 8) + wave) * 64 + lane];
    #pragma unroll 1
    for (int t = wave; t < SEQ; t += 4) {
        const float XiCur = Xi;
        const int tn = (t + 4 < SEQ) ? (t + 4) : t;
        Xi = g_xinv[(((size_t)chain << 8) + tn) * 64 + lane];  // prefetch

        // A = X^{-1} F  (LDS matmul; F shared, symmetric)
        xinvR[lane] = XiCur;
        const float Av = dot8(xinvR + i8f, sF + j8f);
        aRow[lane] = Av;
        aCol[j8f + i] = Av;

        // B = A^T A (bitwise symmetric)
        float Bv = dot8(aCol + i8f, aCol + j8f);

        // eigh(B): sigma^2 in D, V = right singular vectors.
        // 4 SWEEPS REQUIRED (R15: 3 sweeps -> absmax 1.75).
        float V = (i == j) ? 1.0f : 0.0f;
        float D = bpf(j36, Bv);
        #pragma unroll 1
        for (int sw = 0; sw < 4; ++sw) {
            jround_d<1>(Bv, V, D, lane4, j36, tr4, sg1);
            jround_d<2>(Bv, V, D, lane4, j36, tr4, sg2);
            jround_d<3>(Bv, V, D, lane4, j36, tr4, sg2);
            jround_d<4>(Bv, V, D, lane4, j36, tr4, sg4);
            jround_d<5>(Bv, V, D, lane4, j36, tr4, sg4);
            jround_d<6>(Bv, V, D, lane4, j36, tr4, sg4);
            jround_d<7>(Bv, V, D, lane4, j36, tr4, sg4);
        }
        const float sig2 = fmaxf(D, 1e-20f);
        const float g = (0.34657359028f * log2f_(sig2)) * rsqf(sig2);

        // T1 = A V ; C = V^T T1
        vCol[j8f + i] = V;
        const float T1 = dot8(aRow + i8f, vCol + j8f);
        tCol[j8f + i] = T1;
        const float C = dot8(vCol + i8f, tCol + j8f);

        // P_ij = g_j C_ij ; dist = sum P_ij P_ji
        const float P  = g * C;
        const float Pt = bpf(tr4, P);
        const float total = wave_sum63(P * Pt);
        if (lane == 63) out[(chain << 8) + t] = total;
    }
}

extern "C" void kernel_launch(void* const* d_in, const int* in_sizes, int n_in,
                              void* d_out, int out_size, void* d_ws, size_t ws_size,
                              hipStream_t stream) {
    const float* x = (const float*)d_in[0];
    float* out = (float*)d_out;
    (void)in_sizes; (void)n_in; (void)d_ws; (void)ws_size; (void)out_size;

    // One block per chain: wave 0 = fm scan, waves 1-3 = X^{-1} precompute,
    // then all 4 waves = distances for the chain's 256 matrices.
    hipLaunchKernelGGL(fused_kernel, dim3(NCHAIN), dim3(256), 0, stream, x, out);
}

// Round 18
// 1737.479 us; speedup vs baseline: 1.0076x; 1.0076x over previous
//
#include <hip/hip_runtime.h>
#include <stdint.h>

// Problem constants (B=32, C1=64, C2=16, C3=16, N=8)
#define EPSF    1e-10f
#define NCHAIN  2048        // B*C1
#define SEQ     256         // C2*C3
#define NMAT    (NCHAIN*SEQ)

__device__ __forceinline__ float rcpf(float x) { return __builtin_amdgcn_rcpf(x); }
__device__ __forceinline__ float rsqf(float x) { return __builtin_amdgcn_rsqf(x); }
__device__ __forceinline__ float exp2f_(float x) { return __builtin_amdgcn_exp2f(x); }
__device__ __forceinline__ float log2f_(float x) { return __builtin_amdgcn_logf(x); }

// bpermute with pre-shifted (byte) address
__device__ __forceinline__ float bpf(int addr4, float v) {
    return __int_as_float(__builtin_amdgcn_ds_bpermute(addr4, __float_as_int(v)));
}
// uniform-lane broadcast (diagonal pivots)
__device__ __forceinline__ float rlf(float v, int srcLane) {
    return __int_as_float(__builtin_amdgcn_readlane(__float_as_int(v), srcLane));
}
// lane-XOR shuffle via ds_swizzle immediate (DS pipe), mask < 32
template<int MASK>
__device__ __forceinline__ float sxf(float v) {
    static_assert(MASK > 0 && MASK < 32, "swizzle mask");
    return __int_as_float(__builtin_amdgcn_ds_swizzle(
        __float_as_int(v), (MASK << 10) | 0x1F));
}
// DPP mov: cross-lane on the VALU pipe, zero DS cost.
template<int CTRL, int RMASK = 0xF, bool BC = true>
__device__ __forceinline__ float dppf(float v) {
    return __int_as_float(__builtin_amdgcn_update_dpp(
        0, __float_as_int(v), CTRL, RMASK, 0xF, BC));
}
// lane XOR M (M=1..7, column bits) entirely via DPP
template<int M>
__device__ __forceinline__ float cxf(float v) {
    if constexpr      (M == 1) return dppf<0xB1>(v);
    else if constexpr (M == 2) return dppf<0x4E>(v);
    else if constexpr (M == 3) return dppf<0x1B>(v);
    else if constexpr (M == 4) return dppf<0x141>(dppf<0x1B>(v));  // 7^3
    else if constexpr (M == 5) return dppf<0x141>(dppf<0x4E>(v));  // 7^2
    else if constexpr (M == 6) return dppf<0x141>(dppf<0xB1>(v));  // 7^1
    else                       return dppf<0x141>(v);              // 7
}
// dist variant: for the 2-DPP masks use one ds_swizzle instead (dist phase
// is VALU-bound; bit-exact same permutation)
template<int M>
__device__ __forceinline__ float cxd(float v) {
    if constexpr (M == 4 || M == 5 || M == 6) return sxf<M>(v);
    else                                      return cxf<M>(v);
}
// lane XOR (M<<3) (row bits): M=1 is DPP, M=2,3 swizzle, M>=4 bpermute
template<int M>
__device__ __forceinline__ float rxf(float v, int lane4) {
    if constexpr      (M == 1)       return dppf<0x128>(v);
    else if constexpr ((M << 3) < 32) return sxf<(M << 3)>(v);
    else                              return bpf(lane4 ^ (M << 5), v);
}
// lane XOR (M*9) (row+col bits): M=1 via 2 DPP, M=2,3 swizzle, M>=4 bpermute
template<int M>
__device__ __forceinline__ float dxf(float v, int lane4) {
    if constexpr      (M == 1)       return dppf<0xB1>(dppf<0x128>(v));
    else if constexpr ((M * 9) < 32)  return sxf<(M * 9)>(v);
    else                              return bpf(lane4 ^ (M * 36), v);
}

// wave64 sum -> lane 63 holds the total
__device__ __forceinline__ float wave_sum63(float v) {
    v += dppf<0x111>(v);                    // += lane-1   (row_shr:1)
    v += dppf<0x112>(v);                    // += lane-2
    v += dppf<0x114>(v);                    // += lane-4
    v += dppf<0x118>(v);                    // += lane-8   -> lane15/31/47/63
    v += dppf<0x142, 0xA, false>(v);        // bcast15 into rows 1,3
    v += dppf<0x143, 0xC, false>(v);        // bcast31 into rows 2,3
    return v;
}

// 8-float dot from two LDS rows (4x ds_read_b128, 2-way bank alias = free)
__device__ __forceinline__ float dot8(const float* __restrict__ a,
                                      const float* __restrict__ b) {
    const float4 a0 = *reinterpret_cast<const float4*>(a);
    const float4 a1 = *reinterpret_cast<const float4*>(a + 4);
    const float4 b0 = *reinterpret_cast<const float4*>(b);
    const float4 b1 = *reinterpret_cast<const float4*>(b + 4);
    float s = a0.x * b0.x;
    s = fmaf(a0.y, b0.y, s); s = fmaf(a0.z, b0.z, s); s = fmaf(a0.w, b0.w, s);
    s = fmaf(a1.x, b1.x, s); s = fmaf(a1.y, b1.y, s); s = fmaf(a1.z, b1.z, s);
    s = fmaf(a1.w, b1.w, s);
    return s;
}

// Jacobi rotation params for pair {j, j^m}. dj = own diag, dm = partner
// diag, apq = pair off-diagonal, sg = tie-break sign (+1 for pair-second).
__device__ __forceinline__ void jrot2(float dj, float dm, float apq, float sg,
                                      float &c, float &bs) {
    const float dd = dj - dm;
    const float h  = apq + apq;
    const float r2 = fmaf(dd, dd, fmaf(h, h, 1e-36f));
    const float rr = rsqf(r2);                          // 1/r
    const float c2 = fmaf(0.5f * fabsf(dd), rr, 0.5f);  // cos^2 = (1+|d|/r)/2
    const float ic = rsqf(c2);                          // 1/c
    const float chi = (dd != 0.0f) ? copysignf(1.0f, dd) : sg;
    const bool  tiny = r2 < 1e-33f;
    c  = tiny ? 1.0f : c2 * ic;                         // sqrt(c2)
    bs = tiny ? 0.0f : apq * chi * rr * ic;             // s*sign
}

// ---- fm round, chain-shortened (2 DS trips serial): all A-neighbor reads
// reference the PRE-round A (parallel with the aqj gather); t1 is formed
// in-lane (bitwise identical to lane (i^M,j)'s col update since column
// params are column-replicated).
template<int M>
__device__ __forceinline__ void jround_fm(float &A, float &W, float &D,
                                          const int lane4, const int j36,
                                          const int tr4, const float sg) {
    const float dmj = cxf<M>(D);                // DPP (parallel)
    const float aqj = bpf(j36 ^ (M << 2), A);   // A[j, j^M] gather: chain head
    const float Ax  = cxf<M>(A);                // A[i,   j^M]  (parallel)
    const float Ay  = rxf<M>(A, lane4);         // A[i^M, j  ]  (parallel)
    const float Az  = dxf<M>(A, lane4);         // A[i^M, j^M]  (parallel)
    const float Wc  = cxf<M>(W);                // (parallel)
    float aj, bj;
    jrot2(D, dmj, aqj, sg, aj, bj);
    const float ai = bpf(tr4, aj);              // chain: 2nd (last) DS trip
    const float bi = bpf(tr4, bj);
    const float t0 = fmaf(bj, Ax, aj * A);      // col update, row i
    const float t1 = fmaf(bj, Az, aj * Ay);     // col update, row i^M
    A = fmaf(bi, t1, ai * t0);                  // row update
    W = fmaf(bj, Wc, aj * W);
    const float d0 = fmaf(bj, aqj, aj * D);
    const float d1 = fmaf(bj, dmj, aj * aqj);
    D = fmaf(bj, d1, aj * d0);
}

// ---- dist round (R7-proven thr form): fewest VALU ops; dist phase is
// VALU-issue-bound at full occupancy so cross-lane work rides the DS pipe.
template<int M>
__device__ __forceinline__ void jround_d(float &A, float &W, float &D,
                                         const int lane4, const int j36,
                                         const int tr4, const float sg) {
    const float dmj = cxd<M>(D);
    const float aqj = bpf(j36 ^ (M << 2), A);   // DS gather
    float aj, bj;
    jrot2(D, dmj, aqj, sg, aj, bj);
    const float ai = bpf(tr4, aj);              // row params = transpose: DS
    const float bi = bpf(tr4, bj);              // DS
    const float Ac = cxd<M>(A);
    A = fmaf(bj, Ac, aj * A);                   // A <- A J
    const float Ar = rxf<M>(A, lane4);          // post-col-update read
    A = fmaf(bi, Ar, ai * A);                   // A <- J^T A
    const float Wc = cxd<M>(W);
    W = fmaf(bj, Wc, aj * W);
    const float d0 = fmaf(bj, aqj, aj * D);
    const float d1 = fmaf(bj, dmj, aj * aqj);
    D = fmaf(bj, d1, aj * d0);
}

// ---------------- Fused kernel v2: one block = one chain -----------------
// Phase 1: wave 0 runs the fm scan (bitwise-identical to R16's fm_kernel);
//          waves 1-3 park at the barrier (zero issue/memory contention --
//          R17 lesson: helper precompute's global traffic slowed the
//          latency-critical scan more than the GJ overlap saved).
// Phase 2: all 4 waves compute the GL-metric distances, bitwise-identical
//          to R16's dist_kernel, with F handed off through LDS and x
//          software-prefetched. 8 blocks/CU -> 32 waves/CU in phase 2.
__global__ void __launch_bounds__(256, 8)
fused_kernel(const float* __restrict__ x, float* __restrict__ out) {
    __shared__ __align__(16) float sF[64];               // FM (phase 2, RO)
    __shared__ __align__(16) float sAr[4][64];           // per-wave slots
    __shared__ __align__(16) float sAc[4][64];
    __shared__ __align__(16) float sVc[4][64];
    __shared__ __align__(16) float sTc[4][64];

    const int wave = threadIdx.x >> 6;
    const int lane = threadIdx.x & 63;
    const int i = lane >> 3, j = lane & 7;
    const int lane4 = lane << 2;
    const int i32_ = i << 5, j4 = j << 2, i4 = i << 2;
    const int i36 = i * 36, j36 = j * 36;
    const int i8f = i << 3, j8f = j << 3;
    const int tr4 = ((j << 3) + i) << 2;
    const int chain = blockIdx.x;

    const float sg1 = (lane & 1) ? 1.0f : -1.0f;
    const float sg2 = (lane & 2) ? 1.0f : -1.0f;
    const float sg4 = (lane & 4) ? 1.0f : -1.0f;

    const float* __restrict__ base = x + (size_t)chain * (SEQ * 64);

    if (wave == 0) {
        // ================= Phase 1: fm scan (wave 0 only) ===============
        float* __restrict__ bufX = sAr[0];
        float* __restrict__ bufF = sAc[0];
        float* __restrict__ bufW = sVc[0];

        // init: Fi = D^{-1/2} L_u^{-1} from X_1 (one-sided elimination)
        float Mv = base[lane];
        float Ev = (i == j) ? 1.0f : 0.0f;
        #pragma unroll
        for (int kk = 0; kk < 8; ++kk) {
            const float piv = rlf(Mv, kk * 9);
            const float rp  = rcpf(piv);
            const float Mik = bpf(i32_ + (kk << 2), Mv);
            const float Mkj = bpf((kk << 5) + j4,   Mv);
            const float Ekj = bpf((kk << 5) + j4,   Ev);
            const float mi  = (i > kk) ? Mik * rp : 0.0f;
            Mv = fmaf(-mi, Mkj, Mv);
            Ev = fmaf(-mi, Ekj, Ev);
        }
        float Fi = rsqf(bpf(i36, Mv)) * Ev;    // D^{-1/2} L_u^{-1}

        float Xnext = base[(1 << 6) + lane];   // prefetch step input

        #pragma unroll 1
        for (int k = 1; k < SEQ; ++k) {
            const float Xv = Xnext;
            const int kn = (k + 1 < SEQ) ? (k + 1) : k;
            Xnext = base[(kn << 6) + lane];
            const float wk = rcpf((float)(k + 1));

            // B = Fi X Fi^T via LDS matmuls (X symmetric)
            bufX[lane] = Xv;
            bufF[lane] = Fi;
            const float Wv = dot8(bufF + i8f, bufX + j8f);   // (Fi X)_ij
            bufW[lane] = Wv;
            float Bv = dot8(bufW + i8f, bufF + j8f);         // (W Fi^T)_ij
            Bv = 0.5f * (Bv + bpf(tr4, Bv));

            // eigh(B): V (from I), lam in D -- adaptive sweeps
            // (R13: 2-sweep tier FAILS 0.219>0.1675; 4/3 passes)
            float D = bpf(j36, Bv);
            float V = (i == j) ? 1.0f : 0.0f;
            const int nswp = (k < 12) ? 4 : 3;
            #pragma unroll 1
            for (int sw = 0; sw < nswp; ++sw) {
                jround_fm<1>(Bv, V, D, lane4, j36, tr4, sg1);
                jround_fm<2>(Bv, V, D, lane4, j36, tr4, sg2);
                jround_fm<3>(Bv, V, D, lane4, j36, tr4, sg2);
                jround_fm<4>(Bv, V, D, lane4, j36, tr4, sg4);
                jround_fm<5>(Bv, V, D, lane4, j36, tr4, sg4);
                jround_fm<6>(Bv, V, D, lane4, j36, tr4, sg4);
                jround_fm<7>(Bv, V, D, lane4, j36, tr4, sg4);
            }

            // Fi' = diag(lam^{-wk/2}) V^T Fi
            const float lamI = fmaxf(bpf(i4, D), EPSF);
            const float si   = exp2f_(-0.5f * wk * log2f_(lamI));
            bufW[j8f + i] = V;                 // V col-major
            bufX[j8f + i] = Fi;                // Fi col-major
            Fi = si * dot8(bufW + i8f, bufX + j8f);
        }

        // M = (Fi^T Fi)^{-1} via Gauss-Jordan -> shared F
        bufX[j8f + i] = Fi;
        float Gv = dot8(bufX + i8f, bufX + j8f);
        float Mw = (i == j) ? 1.0f : 0.0f;
        #pragma unroll
        for (int kk = 0; kk < 8; ++kk) {
            const float pr  = rcpf(rlf(Gv, kk * 9));
            const float gk  = bpf((kk << 5) + j4, Gv) * pr;
            const float mk  = bpf((kk << 5) + j4, Mw) * pr;
            const float gik = bpf(i32_ + (kk << 2), Gv);
            const bool  isk = (i == kk);
            Gv = isk ? gk : fmaf(-gik, gk, Gv);
            Mw = isk ? mk : fmaf(-gik, mk, Mw);
        }
        sF[lane] = Mw;
    }
    // waves 1-3: straight to the barrier (no contention with the scan)

    __syncthreads();

    // ================= Phase 2: distances (all 4 waves) =================
    float* __restrict__ aRow  = sAr[wave];
    float* __restrict__ aCol  = sAc[wave];
    float* __restrict__ vCol  = sVc[wave];
    float* __restrict__ tCol  = sTc[wave];

    float Xpf = base[(wave << 6) + lane];
    #pragma unroll 1
    for (int t = wave; t < SEQ; t += 4) {
        float Xw = Xpf;
        const int tn = (t + 4 < SEQ) ? (t + 4) : t;
        Xpf = base[(tn << 6) + lane];          // prefetch next iteration's X
        float Yv = sF[lane];

        // A = X^{-1} F via pivot-free Gauss-Jordan (bitwise = R16 dist)
        #pragma unroll
        for (int k = 0; k < 8; ++k) {
            const float pr  = rcpf(rlf(Xw, k * 9));
            const float xk  = bpf((k << 5) + j4, Xw) * pr;
            const float yk  = bpf((k << 5) + j4, Yv) * pr;
            const float xik = bpf(i32_ + (k << 2), Xw);
            const bool  isk = (i == k);
            Xw = isk ? xk : fmaf(-xik, xk, Xw);
            Yv = isk ? yk : fmaf(-xik, yk, Yv);
        }
        const float Av = Yv;

        // stage A in LDS (row- and col-major)
        aRow[lane] = Av;
        aCol[j8f + i] = Av;

        // B = A^T A (bitwise symmetric)
        float Bv = dot8(aCol + i8f, aCol + j8f);

        // eigh(B): sigma^2 in D, V = right singular vectors.
        // 4 SWEEPS REQUIRED (R15: 3 sweeps -> absmax 1.75; kappa^2
        // eigenvalue spread + log() amplification, undamped).
        float V = (i == j) ? 1.0f : 0.0f;
        float D = bpf(j36, Bv);
        #pragma unroll 1
        for (int sw = 0; sw < 4; ++sw) {
            jround_d<1>(Bv, V, D, lane4, j36, tr4, sg1);
            jround_d<2>(Bv, V, D, lane4, j36, tr4, sg2);
            jround_d<3>(Bv, V, D, lane4, j36, tr4, sg2);
            jround_d<4>(Bv, V, D, lane4, j36, tr4, sg4);
            jround_d<5>(Bv, V, D, lane4, j36, tr4, sg4);
            jround_d<6>(Bv, V, D, lane4, j36, tr4, sg4);
            jround_d<7>(Bv, V, D, lane4, j36, tr4, sg4);
        }
        const float sig2 = fmaxf(D, 1e-20f);
        const float g = (0.34657359028f * log2f_(sig2)) * rsqf(sig2);

        // T1 = A V ; C = V^T T1
        vCol[j8f + i] = V;
        const float T1 = dot8(aRow + i8f, vCol + j8f);
        tCol[j8f + i] = T1;
        const float C = dot8(vCol + i8f, tCol + j8f);

        // P_ij = g_j C_ij ; dist = sum P_ij P_ji
        const float P  = g * C;
        const float Pt = bpf(tr4, P);
        const float total = wave_sum63(P * Pt);
        if (lane == 63) out[(chain << 8) + t] = total;
    }
}

extern "C" void kernel_launch(void* const* d_in, const int* in_sizes, int n_in,
                              void* d_out, int out_size, void* d_ws, size_t ws_size,
                              hipStream_t stream) {
    const float* x = (const float*)d_in[0];
    float* out = (float*)d_out;
    (void)in_sizes; (void)n_in; (void)d_ws; (void)ws_size; (void)out_size;

    // One block per chain: wave 0 = fm scan, then all 4 waves = distances.
    hipLaunchKernelGGL(fused_kernel, dim3(NCHAIN), dim3(256), 0, stream, x, out);
}

// Round 19
// 1734.274 us; speedup vs baseline: 1.0095x; 1.0018x over previous
//
#include <hip/hip_runtime.h>
#include <stdint.h>

// Problem constants (B=32, C1=64, C2=16, C3=16, N=8)
#define EPSF    1e-10f
#define NCHAIN  2048        // B*C1
#define SEQ     256         // C2*C3
#define NMAT    (NCHAIN*SEQ)

__device__ __forceinline__ float rcpf(float x) { return __builtin_amdgcn_rcpf(x); }
__device__ __forceinline__ float rsqf(float x) { return __builtin_amdgcn_rsqf(x); }
__device__ __forceinline__ float exp2f_(float x) { return __builtin_amdgcn_exp2f(x); }
__device__ __forceinline__ float log2f_(float x) { return __builtin_amdgcn_logf(x); }

// bpermute with pre-shifted (byte) address
__device__ __forceinline__ float bpf(int addr4, float v) {
    return __int_as_float(__builtin_amdgcn_ds_bpermute(addr4, __float_as_int(v)));
}
// uniform-lane broadcast (diagonal pivots)
__device__ __forceinline__ float rlf(float v, int srcLane) {
    return __int_as_float(__builtin_amdgcn_readlane(__float_as_int(v), srcLane));
}
// lane-XOR shuffle via ds_swizzle immediate (DS pipe), mask < 32
template<int MASK>
__device__ __forceinline__ float sxf(float v) {
    static_assert(MASK > 0 && MASK < 32, "swizzle mask");
    return __int_as_float(__builtin_amdgcn_ds_swizzle(
        __float_as_int(v), (MASK << 10) | 0x1F));
}
// DPP mov: cross-lane on the VALU pipe, zero DS cost.
template<int CTRL, int RMASK = 0xF, bool BC = true>
__device__ __forceinline__ float dppf(float v) {
    return __int_as_float(__builtin_amdgcn_update_dpp(
        0, __float_as_int(v), CTRL, RMASK, 0xF, BC));
}
// lane XOR M (M=1..7, column bits) entirely via DPP
template<int M>
__device__ __forceinline__ float cxf(float v) {
    if constexpr      (M == 1) return dppf<0xB1>(v);
    else if constexpr (M == 2) return dppf<0x4E>(v);
    else if constexpr (M == 3) return dppf<0x1B>(v);
    else if constexpr (M == 4) return dppf<0x141>(dppf<0x1B>(v));  // 7^3
    else if constexpr (M == 5) return dppf<0x141>(dppf<0x4E>(v));  // 7^2
    else if constexpr (M == 6) return dppf<0x141>(dppf<0xB1>(v));  // 7^1
    else                       return dppf<0x141>(v);              // 7
}
// dist variant: for the 2-DPP masks use one ds_swizzle instead (dist phase
// is VALU-bound; bit-exact same permutation)
template<int M>
__device__ __forceinline__ float cxd(float v) {
    if constexpr (M == 4 || M == 5 || M == 6) return sxf<M>(v);
    else                                      return cxf<M>(v);
}
// lane XOR (M<<3) (row bits): M=1 is DPP, M=2,3 swizzle, M>=4 bpermute
template<int M>
__device__ __forceinline__ float rxf(float v, int lane4) {
    if constexpr      (M == 1)       return dppf<0x128>(v);
    else if constexpr ((M << 3) < 32) return sxf<(M << 3)>(v);
    else                              return bpf(lane4 ^ (M << 5), v);
}
// lane XOR (M*9) (row+col bits): M=1 via 2 DPP, M=2,3 swizzle, M>=4 bpermute
template<int M>
__device__ __forceinline__ float dxf(float v, int lane4) {
    if constexpr      (M == 1)       return dppf<0xB1>(dppf<0x128>(v));
    else if constexpr ((M * 9) < 32)  return sxf<(M * 9)>(v);
    else                              return bpf(lane4 ^ (M * 36), v);
}

// wave64 sum -> lane 63 holds the total
__device__ __forceinline__ float wave_sum63(float v) {
    v += dppf<0x111>(v);                    // += lane-1   (row_shr:1)
    v += dppf<0x112>(v);                    // += lane-2
    v += dppf<0x114>(v);                    // += lane-4
    v += dppf<0x118>(v);                    // += lane-8   -> lane15/31/47/63
    v += dppf<0x142, 0xA, false>(v);        // bcast15 into rows 1,3
    v += dppf<0x143, 0xC, false>(v);        // bcast31 into rows 2,3
    return v;
}

// 8-float dot from two LDS rows (4x ds_read_b128, 2-way bank alias = free)
__device__ __forceinline__ float dot8(const float* __restrict__ a,
                                      const float* __restrict__ b) {
    const float4 a0 = *reinterpret_cast<const float4*>(a);
    const float4 a1 = *reinterpret_cast<const float4*>(a + 4);
    const float4 b0 = *reinterpret_cast<const float4*>(b);
    const float4 b1 = *reinterpret_cast<const float4*>(b + 4);
    float s = a0.x * b0.x;
    s = fmaf(a0.y, b0.y, s); s = fmaf(a0.z, b0.z, s); s = fmaf(a0.w, b0.w, s);
    s = fmaf(a1.x, b1.x, s); s = fmaf(a1.y, b1.y, s); s = fmaf(a1.z, b1.z, s);
    s = fmaf(a1.w, b1.w, s);
    return s;
}

// Jacobi rotation params for pair {j, j^m}. dj = own diag, dm = partner
// diag, apq = pair off-diagonal, sg = tie-break sign (+1 for pair-second).
__device__ __forceinline__ void jrot2(float dj, float dm, float apq, float sg,
                                      float &c, float &bs) {
    const float dd = dj - dm;
    const float h  = apq + apq;
    const float r2 = fmaf(dd, dd, fmaf(h, h, 1e-36f));
    const float rr = rsqf(r2);                          // 1/r
    const float c2 = fmaf(0.5f * fabsf(dd), rr, 0.5f);  // cos^2 = (1+|d|/r)/2
    const float ic = rsqf(c2);                          // 1/c
    const float chi = (dd != 0.0f) ? copysignf(1.0f, dd) : sg;
    const bool  tiny = r2 < 1e-33f;
    c  = tiny ? 1.0f : c2 * ic;                         // sqrt(c2)
    bs = tiny ? 0.0f : apq * chi * rr * ic;             // s*sign
}

// ---- fm round, chain-shortened (2 DS trips serial): all A-neighbor reads
// reference the PRE-round A (parallel with the aqj gather); t1 is formed
// in-lane (bitwise identical to lane (i^M,j)'s col update since column
// params are column-replicated).
template<int M>
__device__ __forceinline__ void jround_fm(float &A, float &W, float &D,
                                          const int lane4, const int j36,
                                          const int tr4, const float sg) {
    const float dmj = cxf<M>(D);                // DPP (parallel)
    const float aqj = bpf(j36 ^ (M << 2), A);   // A[j, j^M] gather: chain head
    const float Ax  = cxf<M>(A);                // A[i,   j^M]  (parallel)
    const float Ay  = rxf<M>(A, lane4);         // A[i^M, j  ]  (parallel)
    const float Az  = dxf<M>(A, lane4);         // A[i^M, j^M]  (parallel)
    const float Wc  = cxf<M>(W);                // (parallel)
    float aj, bj;
    jrot2(D, dmj, aqj, sg, aj, bj);
    const float ai = bpf(tr4, aj);              // chain: 2nd (last) DS trip
    const float bi = bpf(tr4, bj);
    const float t0 = fmaf(bj, Ax, aj * A);      // col update, row i
    const float t1 = fmaf(bj, Az, aj * Ay);     // col update, row i^M
    A = fmaf(bi, t1, ai * t0);                  // row update
    W = fmaf(bj, Wc, aj * W);
    const float d0 = fmaf(bj, aqj, aj * D);
    const float d1 = fmaf(bj, dmj, aj * aqj);
    D = fmaf(bj, d1, aj * d0);
}

// ---- dist round (R7-proven thr form): fewest VALU ops; dist phase is
// VALU-issue-bound at full occupancy so cross-lane work rides the DS pipe.
template<int M>
__device__ __forceinline__ void jround_d(float &A, float &W, float &D,
                                         const int lane4, const int j36,
                                         const int tr4, const float sg) {
    const float dmj = cxd<M>(D);
    const float aqj = bpf(j36 ^ (M << 2), A);   // DS gather
    float aj, bj;
    jrot2(D, dmj, aqj, sg, aj, bj);
    const float ai = bpf(tr4, aj);              // row params = transpose: DS
    const float bi = bpf(tr4, bj);              // DS
    const float Ac = cxd<M>(A);
    A = fmaf(bj, Ac, aj * A);                   // A <- A J
    const float Ar = rxf<M>(A, lane4);          // post-col-update read
    A = fmaf(bi, Ar, ai * A);                   // A <- J^T A
    const float Wc = cxd<M>(W);
    W = fmaf(bj, Wc, aj * W);
    const float d0 = fmaf(bj, aqj, aj * D);
    const float d1 = fmaf(bj, dmj, aj * aqj);
    D = fmaf(bj, d1, aj * d0);
}

// ---------------- Fused kernel v2: one block = one chain -----------------
// Phase 1: wave 0 runs the fm scan (bitwise-identical to R16's fm_kernel);
//          waves 1-3 park at the barrier (zero issue/memory contention --
//          R17 lesson: helper precompute's global traffic slowed the
//          latency-critical scan more than the GJ overlap saved).
// Phase 2: all 4 waves compute the GL-metric distances, bitwise-identical
//          to R16's dist_kernel, with F handed off through LDS and x
//          software-prefetched. 8 blocks/CU -> 32 waves/CU in phase 2.
__global__ void __launch_bounds__(256, 8)
fused_kernel(const float* __restrict__ x, float* __restrict__ out) {
    __shared__ __align__(16) float sF[64];               // FM (phase 2, RO)
    __shared__ __align__(16) float sAr[4][64];           // per-wave slots
    __shared__ __align__(16) float sAc[4][64];
    __shared__ __align__(16) float sVc[4][64];
    __shared__ __align__(16) float sTc[4][64];

    const int wave = threadIdx.x >> 6;
    const int lane = threadIdx.x & 63;
    const int i = lane >> 3, j = lane & 7;
    const int lane4 = lane << 2;
    const int i32_ = i << 5, j4 = j << 2, i4 = i << 2;
    const int i36 = i * 36, j36 = j * 36;
    const int i8f = i << 3, j8f = j << 3;
    const int tr4 = ((j << 3) + i) << 2;
    const int chain = blockIdx.x;

    const float sg1 = (lane & 1) ? 1.0f : -1.0f;
    const float sg2 = (lane & 2) ? 1.0f : -1.0f;
    const float sg4 = (lane & 4) ? 1.0f : -1.0f;

    const float* __restrict__ base = x + (size_t)chain * (SEQ * 64);

    if (wave == 0) {
        // ================= Phase 1: fm scan (wave 0 only) ===============
        float* __restrict__ bufX = sAr[0];
        float* __restrict__ bufF = sAc[0];
        float* __restrict__ bufW = sVc[0];

        // init: Fi = D^{-1/2} L_u^{-1} from X_1 (one-sided elimination)
        float Mv = base[lane];
        float Ev = (i == j) ? 1.0f : 0.0f;
        #pragma unroll
        for (int kk = 0; kk < 8; ++kk) {
            const float piv = rlf(Mv, kk * 9);
            const float rp  = rcpf(piv);
            const float Mik = bpf(i32_ + (kk << 2), Mv);
            const float Mkj = bpf((kk << 5) + j4,   Mv);
            const float Ekj = bpf((kk << 5) + j4,   Ev);
            const float mi  = (i > kk) ? Mik * rp : 0.0f;
            Mv = fmaf(-mi, Mkj, Mv);
            Ev = fmaf(-mi, Ekj, Ev);
        }
        float Fi = rsqf(bpf(i36, Mv)) * Ev;    // D^{-1/2} L_u^{-1}

        float Xnext = base[(1 << 6) + lane];   // prefetch step input

        #pragma unroll 1
        for (int k = 1; k < SEQ; ++k) {
            const float Xv = Xnext;
            const int kn = (k + 1 < SEQ) ? (k + 1) : k;
            Xnext = base[(kn << 6) + lane];
            const float wk = rcpf((float)(k + 1));

            // B = Fi X Fi^T via LDS matmuls (X symmetric)
            bufX[lane] = Xv;
            bufF[lane] = Fi;
            const float Wv = dot8(bufF + i8f, bufX + j8f);   // (Fi X)_ij
            bufW[lane] = Wv;
            float Bv = dot8(bufW + i8f, bufF + j8f);         // (W Fi^T)_ij
            Bv = 0.5f * (Bv + bpf(tr4, Bv));

            // eigh(B): V (from I), lam in D -- adaptive sweeps
            // (R13: 2-sweep tier FAILS 0.219>0.1675; 4/3 passes)
            float D = bpf(j36, Bv);
            float V = (i == j) ? 1.0f : 0.0f;
            const int nswp = (k < 12) ? 4 : 3;
            #pragma unroll 1
            for (int sw = 0; sw < nswp; ++sw) {
                jround_fm<1>(Bv, V, D, lane4, j36, tr4, sg1);
                jround_fm<2>(Bv, V, D, lane4, j36, tr4, sg2);
                jround_fm<3>(Bv, V, D, lane4, j36, tr4, sg2);
                jround_fm<4>(Bv, V, D, lane4, j36, tr4, sg4);
                jround_fm<5>(Bv, V, D, lane4, j36, tr4, sg4);
                jround_fm<6>(Bv, V, D, lane4, j36, tr4, sg4);
                jround_fm<7>(Bv, V, D, lane4, j36, tr4, sg4);
            }

            // Fi' = diag(lam^{-wk/2}) V^T Fi
            const float lamI = fmaxf(bpf(i4, D), EPSF);
            const float si   = exp2f_(-0.5f * wk * log2f_(lamI));
            bufW[j8f + i] = V;                 // V col-major
            bufX[j8f + i] = Fi;                // Fi col-major
            Fi = si * dot8(bufW + i8f, bufX + j8f);
        }

        // M = (Fi^T Fi)^{-1} via Gauss-Jordan -> shared F
        bufX[j8f + i] = Fi;
        float Gv = dot8(bufX + i8f, bufX + j8f);
        float Mw = (i == j) ? 1.0f : 0.0f;
        #pragma unroll
        for (int kk = 0; kk < 8; ++kk) {
            const float pr  = rcpf(rlf(Gv, kk * 9));
            const float gk  = bpf((kk << 5) + j4, Gv) * pr;
            const float mk  = bpf((kk << 5) + j4, Mw) * pr;
            const float gik = bpf(i32_ + (kk << 2), Gv);
            const bool  isk = (i == kk);
            Gv = isk ? gk : fmaf(-gik, gk, Gv);
            Mw = isk ? mk : fmaf(-gik, mk, Mw);
        }
        sF[lane] = Mw;
    }
    // waves 1-3: straight to the barrier (no contention with the scan)

    __syncthreads();

    // ================= Phase 2: distances (all 4 waves) =================
    float* __restrict__ aRow  = sAr[wave];
    float* __restrict__ aCol  = sAc[wave];
    float* __restrict__ vCol  = sVc[wave];
    float* __restrict__ tCol  = sTc[wave];

    float Xpf = base[(wave << 6) + lane];
    #pragma unroll 1
    for (int t = wave; t < SEQ; t += 4) {
        float Xw = Xpf;
        const int tn = (t + 4 < SEQ) ? (t + 4) : t;
        Xpf = base[(tn << 6) + lane];          // prefetch next iteration's X
        float Yv = sF[lane];

        // A = X^{-1} F via pivot-free Gauss-Jordan (bitwise = R16 dist)
        #pragma unroll
        for (int k = 0; k < 8; ++k) {
            const float pr  = rcpf(rlf(Xw, k * 9));
            const float xk  = bpf((k << 5) + j4, Xw) * pr;
            const float yk  = bpf((k << 5) + j4, Yv) * pr;
            const float xik = bpf(i32_ + (k << 2), Xw);
            const bool  isk = (i == k);
            Xw = isk ? xk : fmaf(-xik, xk, Xw);
            Yv = isk ? yk : fmaf(-xik, yk, Yv);
        }
        const float Av = Yv;

        // stage A in LDS (row- and col-major)
        aRow[lane] = Av;
        aCol[j8f + i] = Av;

        // B = A^T A (bitwise symmetric)
        float Bv = dot8(aCol + i8f, aCol + j8f);

        // eigh(B): sigma^2 in D, V = right singular vectors.
        // 4 SWEEPS REQUIRED (R15: 3 sweeps -> absmax 1.75; kappa^2
        // eigenvalue spread + log() amplification, undamped).
        float V = (i == j) ? 1.0f : 0.0f;
        float D = bpf(j36, Bv);
        #pragma unroll 1
        for (int sw = 0; sw < 4; ++sw) {
            jround_d<1>(Bv, V, D, lane4, j36, tr4, sg1);
            jround_d<2>(Bv, V, D, lane4, j36, tr4, sg2);
            jround_d<3>(Bv, V, D, lane4, j36, tr4, sg2);
            jround_d<4>(Bv, V, D, lane4, j36, tr4, sg4);
            jround_d<5>(Bv, V, D, lane4, j36, tr4, sg4);
            jround_d<6>(Bv, V, D, lane4, j36, tr4, sg4);
            jround_d<7>(Bv, V, D, lane4, j36, tr4, sg4);
        }
        const float sig2 = fmaxf(D, 1e-20f);
        const float g = (0.34657359028f * log2f_(sig2)) * rsqf(sig2);

        // T1 = A V ; C = V^T T1
        vCol[j8f + i] = V;
        const float T1 = dot8(aRow + i8f, vCol + j8f);
        tCol[j8f + i] = T1;
        const float C = dot8(vCol + i8f, tCol + j8f);

        // P_ij = g_j C_ij ; dist = sum P_ij P_ji
        const float P  = g * C;
        const float Pt = bpf(tr4, P);
        const float total = wave_sum63(P * Pt);
        if (lane == 63) out[(chain << 8) + t] = total;
    }
}

extern "C" void kernel_launch(void* const* d_in, const int* in_sizes, int n_in,
                              void* d_out, int out_size, void* d_ws, size_t ws_size,
                              hipStream_t stream) {
    const float* x = (const float*)d_in[0];
    float* out = (float*)d_out;
    (void)in_sizes; (void)n_in; (void)d_ws; (void)ws_size; (void)out_size;

    // One block per chain: wave 0 = fm scan, then all 4 waves = distances.
    hipLaunchKernelGGL(fused_kernel, dim3(NCHAIN), dim3(256), 0, stream, x, out);
}

// Round 20
// 1689.376 us; speedup vs baseline: 1.0363x; 1.0266x over previous
//
#include <hip/hip_runtime.h>
#include <stdint.h>

// Problem constants (B=32, C1=64, C2=16, C3=16, N=8)
#define EPSF    1e-10f
#define NCHAIN  2048        // B*C1
#define SEQ     256         // C2*C3
#define NMAT    (NCHAIN*SEQ)

// Fréchet means live here between the two kernels (512 KB, fully
// rewritten by fm_kernel on every call -> deterministic).
__device__ float g_fm[NCHAIN * 64];

__device__ __forceinline__ float rcpf(float x) { return __builtin_amdgcn_rcpf(x); }
__device__ __forceinline__ float rsqf(float x) { return __builtin_amdgcn_rsqf(x); }
__device__ __forceinline__ float exp2f_(float x) { return __builtin_amdgcn_exp2f(x); }
__device__ __forceinline__ float log2f_(float x) { return __builtin_amdgcn_logf(x); }

// bpermute with pre-shifted (byte) address
__device__ __forceinline__ float bpf(int addr4, float v) {
    return __int_as_float(__builtin_amdgcn_ds_bpermute(addr4, __float_as_int(v)));
}
// uniform-lane broadcast (diagonal pivots)
__device__ __forceinline__ float rlf(float v, int srcLane) {
    return __int_as_float(__builtin_amdgcn_readlane(__float_as_int(v), srcLane));
}
// lane-XOR shuffle via ds_swizzle immediate (DS pipe), mask < 32
template<int MASK>
__device__ __forceinline__ float sxf(float v) {
    static_assert(MASK > 0 && MASK < 32, "swizzle mask");
    return __int_as_float(__builtin_amdgcn_ds_swizzle(
        __float_as_int(v), (MASK << 10) | 0x1F));
}
// DPP mov: cross-lane on the VALU pipe, zero DS cost.
template<int CTRL, int RMASK = 0xF, bool BC = true>
__device__ __forceinline__ float dppf(float v) {
    return __int_as_float(__builtin_amdgcn_update_dpp(
        0, __float_as_int(v), CTRL, RMASK, 0xF, BC));
}
// lane XOR M (M=1..7, column bits) entirely via DPP
template<int M>
__device__ __forceinline__ float cxf(float v) {
    if constexpr      (M == 1) return dppf<0xB1>(v);
    else if constexpr (M == 2) return dppf<0x4E>(v);
    else if constexpr (M == 3) return dppf<0x1B>(v);
    else if constexpr (M == 4) return dppf<0x141>(dppf<0x1B>(v));  // 7^3
    else if constexpr (M == 5) return dppf<0x141>(dppf<0x4E>(v));  // 7^2
    else if constexpr (M == 6) return dppf<0x141>(dppf<0xB1>(v));  // 7^1
    else                       return dppf<0x141>(v);              // 7
}
// dist variant: for the 2-DPP masks use one ds_swizzle instead (dist is
// VALU-bound, DS pipe has headroom; bit-exact same permutation)
template<int M>
__device__ __forceinline__ float cxd(float v) {
    if constexpr (M == 4 || M == 5 || M == 6) return sxf<M>(v);
    else                                      return cxf<M>(v);
}
// lane XOR (M<<3) (row bits): M=1 is DPP, M=2,3 swizzle, M>=4 bpermute
template<int M>
__device__ __forceinline__ float rxf(float v, int lane4) {
    if constexpr      (M == 1)       return dppf<0x128>(v);
    else if constexpr ((M << 3) < 32) return sxf<(M << 3)>(v);
    else                              return bpf(lane4 ^ (M << 5), v);
}
// lane XOR (M*9) (row+col bits): M=1 via 2 DPP, M=2,3 swizzle, M>=4 bpermute
template<int M>
__device__ __forceinline__ float dxf(float v, int lane4) {
    if constexpr      (M == 1)       return dppf<0xB1>(dppf<0x128>(v));
    else if constexpr ((M * 9) < 32)  return sxf<(M * 9)>(v);
    else                              return bpf(lane4 ^ (M * 36), v);
}

// wave64 sum -> lane 63 holds the total
__device__ __forceinline__ float wave_sum63(float v) {
    v += dppf<0x111>(v);                    // += lane-1   (row_shr:1)
    v += dppf<0x112>(v);                    // += lane-2
    v += dppf<0x114>(v);                    // += lane-4
    v += dppf<0x118>(v);                    // += lane-8   -> lane15/31/47/63
    v += dppf<0x142, 0xA, false>(v);        // bcast15 into rows 1,3
    v += dppf<0x143, 0xC, false>(v);        // bcast31 into rows 2,3
    return v;
}

// 8-float dot from two LDS rows (4x ds_read_b128, 2-way bank alias = free)
__device__ __forceinline__ float dot8(const float* __restrict__ a,
                                      const float* __restrict__ b) {
    const float4 a0 = *reinterpret_cast<const float4*>(a);
    const float4 a1 = *reinterpret_cast<const float4*>(a + 4);
    const float4 b0 = *reinterpret_cast<const float4*>(b);
    const float4 b1 = *reinterpret_cast<const float4*>(b + 4);
    float s = a0.x * b0.x;
    s = fmaf(a0.y, b0.y, s); s = fmaf(a0.z, b0.z, s); s = fmaf(a0.w, b0.w, s);
    s = fmaf(a1.x, b1.x, s); s = fmaf(a1.y, b1.y, s); s = fmaf(a1.z, b1.z, s);
    s = fmaf(a1.w, b1.w, s);
    return s;
}

// Jacobi rotation params for pair {j, j^m}. dj = own diag, dm = partner
// diag, apq = pair off-diagonal, sg = tie-break sign (+1 for pair-second).
__device__ __forceinline__ void jrot2(float dj, float dm, float apq, float sg,
                                      float &c, float &bs) {
    const float dd = dj - dm;
    const float h  = apq + apq;
    const float r2 = fmaf(dd, dd, fmaf(h, h, 1e-36f));
    const float rr = rsqf(r2);                          // 1/r
    const float c2 = fmaf(0.5f * fabsf(dd), rr, 0.5f);  // cos^2 = (1+|d|/r)/2
    const float ic = rsqf(c2);                          // 1/c
    const float chi = (dd != 0.0f) ? copysignf(1.0f, dd) : sg;
    const bool  tiny = r2 < 1e-33f;
    c  = tiny ? 1.0f : c2 * ic;                         // sqrt(c2)
    bs = tiny ? 0.0f : apq * chi * rr * ic;             // s*sign
}

// ---- fm round, chain-shortened (2 DS trips serial): all A-neighbor reads
// reference the PRE-round A (parallel with the aqj gather); t1 is formed
// in-lane (bitwise identical to lane (i^M,j)'s col update since column
// params are column-replicated).
template<int M>
__device__ __forceinline__ void jround_fm(float &A, float &W, float &D,
                                          const int lane4, const int j36,
                                          const int tr4, const float sg) {
    const float dmj = cxf<M>(D);                // DPP (parallel)
    const float aqj = bpf(j36 ^ (M << 2), A);   // A[j, j^M] gather: chain head
    const float Ax  = cxf<M>(A);                // A[i,   j^M]  (parallel)
    const float Ay  = rxf<M>(A, lane4);         // A[i^M, j  ]  (parallel)
    const float Az  = dxf<M>(A, lane4);         // A[i^M, j^M]  (parallel)
    const float Wc  = cxf<M>(W);                // (parallel)
    float aj, bj;
    jrot2(D, dmj, aqj, sg, aj, bj);
    const float ai = bpf(tr4, aj);              // chain: 2nd (last) DS trip
    const float bi = bpf(tr4, bj);
    const float t0 = fmaf(bj, Ax, aj * A);      // col update, row i
    const float t1 = fmaf(bj, Az, aj * Ay);     // col update, row i^M
    A = fmaf(bi, t1, ai * t0);                  // row update
    W = fmaf(bj, Wc, aj * W);
    const float d0 = fmaf(bj, aqj, aj * D);
    const float d1 = fmaf(bj, dmj, aj * aqj);
    D = fmaf(bj, d1, aj * d0);
}

// ---- dist round (R7-proven thr form): fewest VALU ops; dist is VALU-
// issue-bound at ~29 waves/CU so cross-lane work rides the DS pipe.
template<int M>
__device__ __forceinline__ void jround_d(float &A, float &W, float &D,
                                         const int lane4, const int j36,
                                         const int tr4, const float sg) {
    const float dmj = cxd<M>(D);
    const float aqj = bpf(j36 ^ (M << 2), A);   // DS gather
    float aj, bj;
    jrot2(D, dmj, aqj, sg, aj, bj);
    const float ai = bpf(tr4, aj);              // row params = transpose: DS
    const float bi = bpf(tr4, bj);              // DS
    const float Ac = cxd<M>(A);
    A = fmaf(bj, Ac, aj * A);                   // A <- A J
    const float Ar = rxf<M>(A, lane4);          // post-col-update read
    A = fmaf(bi, Ar, ai * A);                   // A <- J^T A
    const float Wc = cxd<M>(W);
    W = fmaf(bj, Wc, aj * W);
    const float d0 = fmaf(bj, aqj, aj * D);
    const float d1 = fmaf(bj, dmj, aj * aqj);
    D = fmaf(bj, d1, aj * d0);
}

// ---------------- Phase 1: recursive Frechet mean (sequential scan) -------
// Inverse-factor recursion (factor-invariance of the affine metric):
//   carry Fi with M = F F^T, F = Fi^{-1}.
//   step:  B = Fi X Fi^T;  eigh(B) -> V, lam;
//          Fi' = diag(lam^{-w/2}) V^T Fi.
// ADAPTIVE SWEEPS (R13: 2-sweep tier FAILS 0.219>0.1675; 4/3 passes):
//   k < 12: 4 sweeps | else: 3 sweeps.  fm tolerates 3 sweeps because its
//   B is near-identity (well-conditioned) AND the w=1/(k+1) power damps
//   residuals; dist does NOT (R15: 3-sweep dist -> absmax 1.75).
// X_{k+1} is software-prefetched one step ahead so HBM/L2 latency sits
// outside the step's serial dependency chain.
__global__ void __launch_bounds__(256, 2)
fm_kernel(const float* __restrict__ x) {
    __shared__ __align__(16) float sA[4][64], sB[4][64], sC[4][64];
    const int w = threadIdx.x >> 6;
    float* __restrict__ bufX = sA[w];   // X row-major / Fi col-major
    float* __restrict__ bufF = sB[w];   // Fi row-major
    float* __restrict__ bufW = sC[w];   // W row-major / V col-major

    const int wid  = (blockIdx.x << 2) + w;                    // chain id
    const int lane = threadIdx.x & 63;
    const int i = lane >> 3, j = lane & 7;
    const int lane4 = lane << 2;
    const int i32_ = i << 5, j4 = j << 2, i4 = i << 2;
    const int i36 = i * 36, j36 = j * 36;
    const int i8f = i << 3, j8f = j << 3;
    const int tr4 = ((j << 3) + i) << 2;

    const float sg1 = (lane & 1) ? 1.0f : -1.0f;
    const float sg2 = (lane & 2) ? 1.0f : -1.0f;
    const float sg4 = (lane & 4) ? 1.0f : -1.0f;

    const float* __restrict__ base = x + (size_t)wid * (SEQ * 64);

    // ---- init: Fi = D^{-1/2} L_u^{-1} from X_1 (one-sided elimination) ---
    float Mv = base[lane];
    float Ev = (i == j) ? 1.0f : 0.0f;
    #pragma unroll
    for (int kk = 0; kk < 8; ++kk) {
        const float piv = rlf(Mv, kk * 9);
        const float rp  = rcpf(piv);
        const float Mik = bpf(i32_ + (kk << 2), Mv);
        const float Mkj = bpf((kk << 5) + j4,   Mv);
        const float Ekj = bpf((kk << 5) + j4,   Ev);
        const float mi  = (i > kk) ? Mik * rp : 0.0f;
        Mv = fmaf(-mi, Mkj, Mv);
        Ev = fmaf(-mi, Ekj, Ev);
    }
    float Fi = rsqf(bpf(i36, Mv)) * Ev;        // row-scaled: D^{-1/2} L_u^{-1}

    float Xnext = base[(1 << 6) + lane];       // prefetch X_1's step input

    #pragma unroll 1
    for (int k = 1; k < SEQ; ++k) {
        const float Xv = Xnext;
        const int kn = (k + 1 < SEQ) ? (k + 1) : k;
        Xnext = base[(kn << 6) + lane];        // prefetch next step's X
        const float wk = rcpf((float)(k + 1));

        // ---- B = Fi X Fi^T via LDS matmuls (X symmetric) ----
        bufX[lane] = Xv;                       // X row-major
        bufF[lane] = Fi;                       // Fi row-major
        const float Wv = dot8(bufF + i8f, bufX + j8f);   // (Fi X)_ij
        bufW[lane] = Wv;
        float Bv = dot8(bufW + i8f, bufF + j8f);         // (W Fi^T)_ij
        Bv = 0.5f * (Bv + bpf(tr4, Bv));       // symmetrize

        // ---- eigh(B): V (from I), lam in D -- adaptive sweep count ----
        float D = bpf(j36, Bv);                // col-replicated diag
        float V = (i == j) ? 1.0f : 0.0f;
        const int nswp = (k < 12) ? 4 : 3;
        #pragma unroll 1
        for (int sw = 0; sw < nswp; ++sw) {
            jround_fm<1>(Bv, V, D, lane4, j36, tr4, sg1);
            jround_fm<2>(Bv, V, D, lane4, j36, tr4, sg2);
            jround_fm<3>(Bv, V, D, lane4, j36, tr4, sg2);
            jround_fm<4>(Bv, V, D, lane4, j36, tr4, sg4);
            jround_fm<5>(Bv, V, D, lane4, j36, tr4, sg4);
            jround_fm<6>(Bv, V, D, lane4, j36, tr4, sg4);
            jround_fm<7>(Bv, V, D, lane4, j36, tr4, sg4);
        }

        // ---- Fi' = diag(lam^{-wk/2}) V^T Fi ----
        const float lamI = fmaxf(bpf(i4, D), EPSF);      // lam_i (row index)
        const float si   = exp2f_(-0.5f * wk * log2f_(lamI));
        bufW[j8f + i] = V;                     // V col-major (W consumed)
        bufX[j8f + i] = Fi;                    // Fi col-major (X consumed)
        Fi = si * dot8(bufW + i8f, bufX + j8f);
    }

    // ---- M = (Fi^T Fi)^{-1} via Gauss-Jordan (SPD, one-time) ----
    bufX[j8f + i] = Fi;                        // Fi col-major
    float Gv = dot8(bufX + i8f, bufX + j8f);   // G = Fi^T Fi (bitwise sym)
    float Mw = (i == j) ? 1.0f : 0.0f;
    #pragma unroll
    for (int kk = 0; kk < 8; ++kk) {
        const float pr  = rcpf(rlf(Gv, kk * 9));
        const float gk  = bpf((kk << 5) + j4, Gv) * pr;
        const float mk  = bpf((kk << 5) + j4, Mw) * pr;
        const float gik = bpf(i32_ + (kk << 2), Gv);
        const bool  isk = (i == kk);
        Gv = isk ? gk : fmaf(-gik, gk, Gv);
        Mw = isk ? mk : fmaf(-gik, mk, Mw);
    }
    g_fm[(wid << 6) + lane] = Mw;
}

// ---------------- Phase 2: GL metric distances ----------------------------
// dist = sum_ij (ls_i rsig_i)(ls_j rsig_j) C_ij C_ji,  C = V^T (A V),
// with A = X^{-1} FM, eigh(A^T A) giving sigma^2 (D) and V.
// 4 SWEEPS REQUIRED (R15: 3 sweeps -> absmax 1.75; A^T A has kappa^2
// eigenvalue spread and log(sigma) amplifies small-eigenvalue residuals,
// one-shot into the output with no damping).
__global__ void __launch_bounds__(256, 4)
dist_kernel(const float* __restrict__ x, float* __restrict__ out) {
    __shared__ __align__(16) float sAr[4][64];   // A row-major
    __shared__ __align__(16) float sAc[4][64];   // A col-major
    __shared__ __align__(16) float sVc[4][64];   // V col-major
    __shared__ __align__(16) float sTc[4][64];   // T1 = A*V col-major
    const int w = threadIdx.x >> 6;
    float* __restrict__ aRow = sAr[w];
    float* __restrict__ aCol = sAc[w];
    float* __restrict__ vCol = sVc[w];
    float* __restrict__ tCol = sTc[w];

    const int wid  = (blockIdx.x << 2) + w;                    // matrix id
    const int lane = threadIdx.x & 63;
    const int i = lane >> 3, j = lane & 7;
    const int lane4 = lane << 2;
    const int i32_ = i << 5, j4 = j << 2;
    const int j36 = j * 36;
    const int i8f = i << 3, j8f = j << 3;
    const int tr4 = ((j << 3) + i) << 2;
    const int chain = wid >> 8;                                // / SEQ

    const float sg1 = (lane & 1) ? 1.0f : -1.0f;
    const float sg2 = (lane & 2) ? 1.0f : -1.0f;
    const float sg4 = (lane & 4) ? 1.0f : -1.0f;

    float Xw = x[(size_t)wid * 64 + lane];
    float Yv = g_fm[(chain << 6) + lane];

    // A = X^{-1} FM via pivot-free Gauss-Jordan (X SPD, well-conditioned)
    #pragma unroll
    for (int k = 0; k < 8; ++k) {
        const float pr  = rcpf(rlf(Xw, k * 9));
        const float xk  = bpf((k << 5) + j4, Xw) * pr;
        const float yk  = bpf((k << 5) + j4, Yv) * pr;
        const float xik = bpf(i32_ + (k << 2), Xw);
        const bool  isk = (i == k);
        Xw = isk ? xk : fmaf(-xik, xk, Xw);
        Yv = isk ? yk : fmaf(-xik, yk, Yv);
    }
    const float Av = Yv;

    // stage A in LDS (row- and col-major)
    aRow[lane] = Av;
    aCol[j8f + i] = Av;

    // B = A^T A = colA_i . colA_j  (bitwise symmetric)
    float Bv = dot8(aCol + i8f, aCol + j8f);

    // eigh(B): sigma^2 in D, V = right singular vectors
    float V = (i == j) ? 1.0f : 0.0f;
    float D = bpf(j36, Bv);
    #pragma unroll 1
    for (int sw = 0; sw < 4; ++sw) {
        jround_d<1>(Bv, V, D, lane4, j36, tr4, sg1);
        jround_d<2>(Bv, V, D, lane4, j36, tr4, sg2);
        jround_d<3>(Bv, V, D, lane4, j36, tr4, sg2);
        jround_d<4>(Bv, V, D, lane4, j36, tr4, sg4);
        jround_d<5>(Bv, V, D, lane4, j36, tr4, sg4);
        jround_d<6>(Bv, V, D, lane4, j36, tr4, sg4);
        jround_d<7>(Bv, V, D, lane4, j36, tr4, sg4);
    }
    const float sig2 = fmaxf(D, 1e-20f);
    const float g = (0.34657359028f * log2f_(sig2)) * rsqf(sig2); // ls_j*rsig_j

    // T1 = A V  (rowA_i . colV_j)
    vCol[j8f + i] = V;
    const float T1 = dot8(aRow + i8f, vCol + j8f);

    // C = V^T T1  (colV_i . colT1_j)
    tCol[j8f + i] = T1;
    const float C = dot8(vCol + i8f, tCol + j8f);

    // fold g into C before the single transpose read:
    // P_ij = g_j C_ij ; contrib = P_ij * P_ji
    const float P  = g * C;
    const float Pt = bpf(tr4, P);

    const float total = wave_sum63(P * Pt);    // DPP reduce, 0 DS
    if (lane == 63) out[wid] = total;
}

extern "C" void kernel_launch(void* const* d_in, const int* in_sizes, int n_in,
                              void* d_out, int out_size, void* d_ws, size_t ws_size,
                              hipStream_t stream) {
    const float* x = (const float*)d_in[0];
    float* out = (float*)d_out;
    (void)in_sizes; (void)n_in; (void)d_ws; (void)ws_size; (void)out_size;

    // Phase 1: 2048 chains, 1 wave each, 4 waves/block
    hipLaunchKernelGGL(fm_kernel, dim3(NCHAIN / 4), dim3(256), 0, stream, x);
    // Phase 2: 524288 matrices, 1 wave each
    hipLaunchKernelGGL(dist_kernel, dim3(NMAT / 4), dim3(256), 0, stream, x, out);
}